// Round 3
// baseline (569.726 us; speedup 1.0000x reference)
//
#include <hip/hip_runtime.h>

// MLP_RSNA6: B=500000 rows x 200 fp32; 25 groups x 8 contiguous cols ->
// dot(w1)+b1 -> relu -> h -> 3 outs into 3 contiguous out cols; out=(B,75).
//
// Traffic floor: 400 MB read + 150 MB write = 550 MB -> ~87 us @ 6.3 TB/s.
// R1 (strided direct) and R2 (full LDS staging) tie at ~560 us dur_us ->
// hypothesis: kernel is at HBM floor, dur_us dominated by harness reset
// (1.6 GB poison fill ~250us + 400 MB restore ~130us). R3 triangulates:
// 2x occupancy (32 waves/CU), ONE barrier per tile, ping-pong out buffer,
// grid-stride persistent blocks. If dur_us unchanged -> roofline confirmed.
//
// LDS: 2*32*75*4 + idx = 19.4 KB -> 8 blocks/CU; __launch_bounds__(256,8)
// caps VGPR at 64 for 32 waves/CU (kernel is tiny, no spill expected).

#define GROUPS  25
#define IN_NUM  8
#define ROW     200
#define OUTROW  75
#define OUTT    3
#define RPB     32
#define THREADS 256

__global__ __launch_bounds__(THREADS, 8) void mlp_rsna6_kernel(
    const float* __restrict__ x,
    const float* __restrict__ w1,
    const float* __restrict__ b1,
    const float* __restrict__ w2,
    const float* __restrict__ b2,
    const int*   __restrict__ iok,
    const int*   __restrict__ iov,
    float*       __restrict__ out,
    int nrows)
{
    __shared__ float os[2][RPB * OUTROW];   // ping-pong out tile, 19.2 KB
    __shared__ int   kb_s[GROUPS];
    __shared__ int   vb_s[GROUPS];

    const int tid = threadIdx.x;

    if (tid < GROUPS) {
        kb_s[tid] = iok[tid * IN_NUM];
        vb_s[tid] = iov[tid * OUTT];
    }
    __syncthreads();

    // Hoisted uniform weights (scalar regs).
    const float W10 = w1[0], W11 = w1[1], W12 = w1[2], W13 = w1[3];
    const float W14 = w1[4], W15 = w1[5], W16 = w1[6], W17 = w1[7];
    const float B1  = b1[0];
    const float W20 = w2[0], W21 = w2[1], W22 = w2[2];
    const float B20 = b2[0], B21 = b2[1], B22 = b2[2];

    const int ntiles = (nrows + RPB - 1) / RPB;
    int p = 0;

    for (int t = blockIdx.x; t < ntiles; t += gridDim.x, p ^= 1) {
        const int r0   = t * RPB;
        const int rows = min(RPB, nrows - r0);
        const int items = rows * GROUPS;            // 800 when full

        const float* xbase = x + (size_t)r0 * ROW;

        // ---- compute: global float4 loads (wave-contiguous), LDS out pack ----
        for (int i = tid; i < items; i += THREADS) {
            int bl = i / GROUPS;                    // magic-mul
            int g  = i - bl * GROUPS;

            const float4* xp = reinterpret_cast<const float4*>(
                xbase + bl * ROW + kb_s[g]);
            float4 a0 = xp[0];
            float4 a1 = xp[1];

            float s = B1;
            s = fmaf(a0.x, W10, s);
            s = fmaf(a0.y, W11, s);
            s = fmaf(a0.z, W12, s);
            s = fmaf(a0.w, W13, s);
            s = fmaf(a1.x, W14, s);
            s = fmaf(a1.y, W15, s);
            s = fmaf(a1.z, W16, s);
            s = fmaf(a1.w, W17, s);
            float h = fmaxf(s, 0.0f);

            float* op = &os[p][bl * OUTROW + vb_s[g]];
            op[0] = fmaf(h, W20, B20);
            op[1] = fmaf(h, W21, B21);
            op[2] = fmaf(h, W22, B22);
        }

        __syncthreads();   // the ONLY barrier per tile; also covers the WAR
                           // on os[p] from the store-phase reads 2 tiles ago

        // ---- store: contiguous float4 stream from LDS ----
        float4*       og = reinterpret_cast<float4*>(out + (size_t)r0 * OUTROW);
        const float4* s4 = reinterpret_cast<const float4*>(os[p]);
        const int fl = rows * OUTROW;               // 2400 when full
        const int m4 = fl / 4;                      // 600
        for (int i = tid; i < m4; i += THREADS) og[i] = s4[i];
        for (int i = m4 * 4 + tid; i < fl; i += THREADS)
            out[(size_t)r0 * OUTROW + i] = os[p][i];
        // no trailing sync: next tile writes os[p^1]; its barrier drains
        // this tile's LDS reads before os[p] is reused.
    }
}

extern "C" void kernel_launch(void* const* d_in, const int* in_sizes, int n_in,
                              void* d_out, int out_size, void* d_ws, size_t ws_size,
                              hipStream_t stream) {
    const float* x   = (const float*)d_in[0];
    const float* w1  = (const float*)d_in[1];
    const float* b1  = (const float*)d_in[2];
    const float* w2  = (const float*)d_in[3];
    const float* b2  = (const float*)d_in[4];
    const int*   iok = (const int*)d_in[5];
    const int*   iov = (const int*)d_in[6];
    float*       out = (float*)d_out;

    int nrows = in_sizes[0] / ROW;                  // 500000
    int grid  = 2048;                               // 8 blocks/CU x 256 CUs, grid-stride
    mlp_rsna6_kernel<<<grid, THREADS, 0, stream>>>(
        x, w1, b1, w2, b2, iok, iov, out, nrows);
}